// Round 10
// baseline (223.522 us; speedup 1.0000x reference)
//
#include <hip/hip_runtime.h>

// ImplicitNetOC: u = clip(-pB) ; pB = relu(relu([x,t]W1+b1)W2+b2) @ (W3@Bmat) + b3@Bmat
// R10: co-residency via SMALLER BLOCKS, not fewer registers. 256 threads / 4 waves,
// BM=32, LDS 37.5 KB -> 3+ blocks/CU at the kernel's natural ~137-unified-reg
// footprint (launch_bounds(256,3) budget 170 -> no spill, unlike R6/R7/R9 where
// 8-wave blocks forced a 128 budget and the allocator spilled to scratch).
// Weights stream from ws as pre-packed MFMA A-fragments (R8 scheme).

typedef __bf16 bf16;
typedef __bf16 bf16x8 __attribute__((ext_vector_type(8)));
typedef __bf16 bf16x4 __attribute__((ext_vector_type(4)));
typedef float  f32x4  __attribute__((ext_vector_type(4)));

#define HID    256
#define SDIM   64
#define CDIM   16
#define BM     32
#define GRID   1024     // 4096 tiles / ITERS
#define ITERS  4
#define LDH    264      // bf16 stride (528 B, 16B-aligned rows; 132 dw == 4 mod 32)
#define LDX    72       // bf16 stride (144 B, 16B-aligned; 36 dw == 4 mod 32)

// ws byte offsets (same pack format as R8/R9)
#define OFF_W2P 0        // 8192 entries x 16 B (8kt x 16nt x 64lane)
#define OFF_W3P 131072   // 512 entries x 16 B (8kt x 64lane)
#define OFF_W1P 139264   // 2048 entries x 16 B (2kt x 16nt x 64lane)
#define OFF_B1E 172032   // 256 f32
#define OFF_B3B 173056   // 16 f32

#define MFMA(a, b, c) __builtin_amdgcn_mfma_f32_16x16x32_bf16(a, b, c, 0, 0, 0)

__device__ __forceinline__ int sh_idx(int row, int h) { return row * LDH + h; }

// ---- pack kernel: W2/W1/W3B A-frags + folded biases -> ws. 22 x 512 ----
__global__ __launch_bounds__(512)
void oc_pack(const float* __restrict__ t,  const float* __restrict__ W1,
             const float* __restrict__ b1, const float* __restrict__ W2,
             const float* __restrict__ W3, const float* __restrict__ b3,
             const float* __restrict__ Bmat, char* __restrict__ ws) {
  const int gid = blockIdx.x * 512 + threadIdx.x;
  if (gid < 8192) {
    const int lane = gid & 63, tt = gid >> 6;
    const int nt = tt & 15, kt = tt >> 4;
    const int m = nt * 16 + (lane & 15);
    const int k0 = kt * 32 + ((lane >> 4) << 3);
    bf16x8 v;
#pragma unroll
    for (int j = 0; j < 8; ++j) v[j] = (bf16)W2[(k0 + j) * HID + m];
    *(bf16x8*)((bf16*)(ws + OFF_W2P) + (size_t)gid * 8) = v;
  } else if (gid < 8704) {
    const int e = gid - 8192, kt = e >> 6, fl = e & 63;
    const int r0 = kt * 32 + ((fl >> 4) << 3);
    const int c  = fl & 15;
    float aw[8];
#pragma unroll
    for (int j = 0; j < 8; ++j) aw[j] = 0.f;
    for (int m = 0; m < SDIM; ++m) {
      const float bm = Bmat[m * CDIM + c];
#pragma unroll
      for (int j = 0; j < 8; ++j) aw[j] = fmaf(W3[(r0 + j) * SDIM + m], bm, aw[j]);
    }
    bf16x8 v;
#pragma unroll
    for (int j = 0; j < 8; ++j) v[j] = (bf16)aw[j];
    *(bf16x8*)((bf16*)(ws + OFF_W3P) + (size_t)e * 8) = v;
  } else if (gid < 10752) {
    const int e = gid - 8704;
    const int lane = e & 63, tt = e >> 6;
    const int nt = tt & 15, kt = tt >> 4;
    const int m = nt * 16 + (lane & 15);
    const int k0 = kt * 32 + ((lane >> 4) << 3);
    bf16x8 v;
#pragma unroll
    for (int j = 0; j < 8; ++j) v[j] = (bf16)W1[(k0 + j) * HID + m];
    *(bf16x8*)((bf16*)(ws + OFF_W1P) + (size_t)e * 8) = v;
  } else if (gid < 11008) {
    const int h = gid - 10752;
    ((float*)(ws + OFF_B1E))[h] = b1[h] + t[0] * W1[SDIM * HID + h];  // fold t-col
  } else if (gid < 11024) {
    const int c = gid - 11008;
    float s = 0.f;
    for (int m = 0; m < SDIM; ++m) s = fmaf(b3[m], Bmat[m * CDIM + c], s);
    ((float*)(ws + OFF_B3B))[c] = s;
  }
}

// ---- main: 1024 blocks x 256 threads (4 waves), 37.5 KB LDS -> 3+ blocks/CU ----
__global__ __launch_bounds__(256, 3)
void oc_main(const float* __restrict__ x, const float* __restrict__ b2,
             const char* __restrict__ ws, float* __restrict__ out) {
  __shared__ bf16 sH1[BM * LDH];   // H1 [batch][hidden]; reused as H2-lo
  __shared__ bf16 sH2[BM * LDH];   // H2-hi
  __shared__ bf16 sX [BM * LDX];   // staged X [batch][k]
  const int tid  = threadIdx.x;
  const int wave = tid >> 6, lane = tid & 63;
  const int q    = lane >> 4, l = lane & 15;

  const bf16* W2p = (const bf16*)(ws + OFF_W2P);
  const bf16* W3p = (const bf16*)(ws + OFF_W3P);
  const bf16* W1p = (const bf16*)(ws + OFF_W1P);

  // ---- initial X stage: 512 float4, 2 per thread ----
  {
    const float* xp = x + (size_t)blockIdx.x * BM * SDIM;
#pragma unroll
    for (int i = 0; i < 2; ++i) {
      const int e = i * 256 + tid;           // 512 float4 = 32 x 64 floats
      const int r = e >> 4, k4 = (e & 15) * 4;
      const float4 v = *(const float4*)(xp + r * SDIM + k4);
      bf16x4 w = {(bf16)v.x, (bf16)v.y, (bf16)v.z, (bf16)v.w};
      *(bf16x4*)(&sX[r * LDX + k4]) = w;
    }
  }

  // ---- biases: wave owns 64 hidden (mt 0..3), h0 = 64*wave + 16*mt + 4*q ----
  f32x4 b1e[4], b2e[4];
#pragma unroll
  for (int mt = 0; mt < 4; ++mt) {
    const int h0 = 64 * wave + 16 * mt + 4 * q;
    const float4 v1 = *(const float4*)((const float*)(ws + OFF_B1E) + h0);
    const float4 v2 = *(const float4*)(b2 + h0);
    b1e[mt] = (f32x4){v1.x, v1.y, v1.z, v1.w};
    b2e[mt] = (f32x4){v2.x, v2.y, v2.z, v2.w};
  }
  f32x4 b3t;
  {
    const float4 v = *(const float4*)((const float*)(ws + OFF_B3B) + 4 * q);
    b3t = (f32x4){v.x, v.y, v.z, v.w};
  }
  __syncthreads();   // sX staged

  f32x4 acc[4][2];

  for (int it = 0; it < ITERS; ++it) {
    const int tile = blockIdx.x + it * GRID;

    // ---- layer 1: H1 = relu(W1^T X^T + b1); M=64 hidden/wave, N=32 batch ----
#pragma unroll
    for (int mt = 0; mt < 4; ++mt)
#pragma unroll
      for (int nt = 0; nt < 2; ++nt) acc[mt][nt] = b1e[mt];
#pragma unroll
    for (int kt = 0; kt < 2; ++kt) {
      bf16x8 w1f[4];
#pragma unroll
      for (int mt = 0; mt < 4; ++mt)
        w1f[mt] = *(const bf16x8*)(W1p + ((size_t)(kt * 16 + 4 * wave + mt) * 64 + lane) * 8);
#pragma unroll
      for (int nt = 0; nt < 2; ++nt) {
        const bf16x8 b = *(const bf16x8*)(&sX[(16 * nt + l) * LDX + 32 * kt + 8 * q]);
#pragma unroll
        for (int mt = 0; mt < 4; ++mt) acc[mt][nt] = MFMA(w1f[mt], b, acc[mt][nt]);
      }
    }
#pragma unroll
    for (int mt = 0; mt < 4; ++mt) {
      const int h0 = 64 * wave + 16 * mt + 4 * q;
#pragma unroll
      for (int nt = 0; nt < 2; ++nt) {
        bf16x4 v;
#pragma unroll
        for (int r = 0; r < 4; ++r) v[r] = (bf16)fmaxf(acc[mt][nt][r], 0.f);
        *(bf16x4*)(&sH1[sh_idx(16 * nt + l, h0)]) = v;
      }
    }
    __syncthreads();   // A: H1 visible; sX reads done

    // ---- layer 2: H2 = relu(W2^T H1 + b2)  K=256; W2 frags streamed from ws ----
#pragma unroll
    for (int mt = 0; mt < 4; ++mt)
#pragma unroll
      for (int nt = 0; nt < 2; ++nt) acc[mt][nt] = b2e[mt];
#pragma unroll
    for (int kt = 0; kt < 8; ++kt) {
      bf16x8 w2f[4];
#pragma unroll
      for (int mt = 0; mt < 4; ++mt)
        w2f[mt] = *(const bf16x8*)(W2p + ((size_t)(kt * 16 + 4 * wave + mt) * 64 + lane) * 8);
#pragma unroll
      for (int nt = 0; nt < 2; ++nt) {
        const bf16x8 b = *(const bf16x8*)(&sH1[sh_idx(16 * nt + l, 32 * kt + 8 * q)]);
#pragma unroll
        for (int mt = 0; mt < 4; ++mt) acc[mt][nt] = MFMA(w2f[mt], b, acc[mt][nt]);
      }
    }
    __syncthreads();   // B: sH1 reads done -> overwritable as H2-lo

    // ---- H2 writeback: hi (sH2) + lo residual (sH1), b64 each ----
#pragma unroll
    for (int mt = 0; mt < 4; ++mt) {
      const int h0 = 64 * wave + 16 * mt + 4 * q;
#pragma unroll
      for (int nt = 0; nt < 2; ++nt) {
        bf16x4 hi, lo;
#pragma unroll
        for (int r = 0; r < 4; ++r) {
          const float v = fmaxf(acc[mt][nt][r], 0.f);
          const bf16 h = (bf16)v;
          hi[r] = h;
          lo[r] = (bf16)(v - (float)h);
        }
        const int idx = sh_idx(16 * nt + l, h0);
        *(bf16x4*)(&sH2[idx]) = hi;
        *(bf16x4*)(&sH1[idx]) = lo;
      }
    }
    __syncthreads();   // C: H2 hi/lo visible

    if (wave < 2) {
      // ---- layer 3 (waves 0-1): u = clip(-(W3B^T(H2hi+H2lo) + b3B)), 16 rows/wave ----
      f32x4 a3 = b3t;
#pragma unroll
      for (int kt = 0; kt < 8; ++kt) {
        const bf16x8 w3 = *(const bf16x8*)(W3p + ((size_t)kt * 64 + lane) * 8);
        const int idx = sh_idx(16 * wave + l, 32 * kt + 8 * q);
        const bf16x8 bh = *(const bf16x8*)(&sH2[idx]);
        const bf16x8 bl = *(const bf16x8*)(&sH1[idx]);
        a3 = MFMA(w3, bh, a3);
        a3 = MFMA(w3, bl, a3);
      }
      f32x4 o;
#pragma unroll
      for (int r = 0; r < 4; ++r)
        o[r] = fminf(fmaxf(-a3[r], -1.f), 1.f);
      *(float4*)(&out[((size_t)tile * BM + 16 * wave + l) * CDIM + 4 * q]) = *(float4*)&o;
    } else if (it + 1 < ITERS) {
      // ---- waves 2-3: stage next X tile concurrently with layer 3 ----
      const float* xp = x + (size_t)(tile + GRID) * BM * SDIM;
      const int tid2 = tid - 128;            // 0..127
#pragma unroll
      for (int i = 0; i < 4; ++i) {
        const int e = i * 128 + tid2;        // 512 float4 = 32 x 64 floats
        const int r = e >> 4, k4 = (e & 15) * 4;
        const float4 v = *(const float4*)(xp + r * SDIM + k4);
        bf16x4 w = {(bf16)v.x, (bf16)v.y, (bf16)v.z, (bf16)v.w};
        *(bf16x4*)(&sX[r * LDX + k4]) = w;
      }
    }
    __syncthreads();   // D: L3 reads + stage done before next L1 overwrites sH1/reads sX
  }
}

extern "C" void kernel_launch(void* const* d_in, const int* in_sizes, int n_in,
                              void* d_out, int out_size, void* d_ws, size_t ws_size,
                              hipStream_t stream) {
  const float* x    = (const float*)d_in[0];
  const float* t    = (const float*)d_in[1];
  const float* W1   = (const float*)d_in[2];
  const float* b1   = (const float*)d_in[3];
  const float* W2   = (const float*)d_in[4];
  const float* b2   = (const float*)d_in[5];
  const float* W3   = (const float*)d_in[6];
  const float* b3   = (const float*)d_in[7];
  const float* Bmat = (const float*)d_in[8];
  float* out = (float*)d_out;
  char*  ws  = (char*)d_ws;

  hipLaunchKernelGGL(oc_pack, dim3(22), dim3(512), 0, stream,
                     t, W1, b1, W2, W3, b3, Bmat, ws);
  hipLaunchKernelGGL(oc_main, dim3(GRID), dim3(256), 0, stream,
                     x, b2, ws, out);
}

// Round 11
// 162.009 us; speedup vs baseline: 1.3797x; 1.3797x over previous
//
#include <hip/hip_runtime.h>

// ImplicitNetOC: u = clip(-pB) ; pB = relu(relu([x,t]W1+b1)W2+b2) @ (W3@Bmat) + b3@Bmat
// R11: two co-resident blocks WITHOUT tightening the register budget.
// Rule learned (R6/R7/R9/R10): any launch_bounds budget < 256 regs makes this
// compiler spill the streamed-fragment pipeline. So keep the 256-reg budget
// (2 waves/EU) and shrink the BLOCK to 4 waves (256 thr): 1 wave/EU per block
// -> 2 blocks/CU co-resident, LDS 2 x 76.8 KB = 153.6 <= 160 KB. Per-CU work
// identical to R8; barriers now split into two independent domains.

typedef __bf16 bf16;
typedef __bf16 bf16x8 __attribute__((ext_vector_type(8)));
typedef __bf16 bf16x4 __attribute__((ext_vector_type(4)));
typedef float  f32x4  __attribute__((ext_vector_type(4)));

#define HID    256
#define SDIM   64
#define CDIM   16
#define BM     64
#define GRID   512      // 2 blocks per CU
#define ITERS  4        // 131072 / (BM*GRID)
#define LDH    264      // bf16 stride (528 B, 16B-aligned; 132 dw == 4 mod 32 banks)
#define LDX    72       // bf16 stride (144 B, 16B-aligned; 36 dw == 4 mod 32 banks)

// ws byte offsets (pack format unchanged from R8)
#define OFF_W2P 0        // 8192 entries x 16 B (8kt x 16nt x 64lane)
#define OFF_W3P 131072   // 512 entries x 16 B (8kt x 64lane)
#define OFF_W1P 139264   // 2048 entries x 16 B (2kt x 16nt x 64lane)
#define OFF_B1E 172032   // 256 f32
#define OFF_B3B 173056   // 16 f32

#define MFMA(a, b, c) __builtin_amdgcn_mfma_f32_16x16x32_bf16(a, b, c, 0, 0, 0)

__device__ __forceinline__ int sh_idx(int row, int h) { return row * LDH + h; }

// ---- pack kernel: W2/W1/W3B A-frags + folded biases -> ws. 22 x 512 ----
__global__ __launch_bounds__(512)
void oc_pack(const float* __restrict__ t,  const float* __restrict__ W1,
             const float* __restrict__ b1, const float* __restrict__ W2,
             const float* __restrict__ W3, const float* __restrict__ b3,
             const float* __restrict__ Bmat, char* __restrict__ ws) {
  const int gid = blockIdx.x * 512 + threadIdx.x;
  if (gid < 8192) {
    const int lane = gid & 63, tt = gid >> 6;
    const int nt = tt & 15, kt = tt >> 4;
    const int m = nt * 16 + (lane & 15);
    const int k0 = kt * 32 + ((lane >> 4) << 3);
    bf16x8 v;
#pragma unroll
    for (int j = 0; j < 8; ++j) v[j] = (bf16)W2[(k0 + j) * HID + m];
    *(bf16x8*)((bf16*)(ws + OFF_W2P) + (size_t)gid * 8) = v;
  } else if (gid < 8704) {
    const int e = gid - 8192, kt = e >> 6, fl = e & 63;
    const int r0 = kt * 32 + ((fl >> 4) << 3);
    const int c  = fl & 15;
    float aw[8];
#pragma unroll
    for (int j = 0; j < 8; ++j) aw[j] = 0.f;
    for (int m = 0; m < SDIM; ++m) {
      const float bm = Bmat[m * CDIM + c];
#pragma unroll
      for (int j = 0; j < 8; ++j) aw[j] = fmaf(W3[(r0 + j) * SDIM + m], bm, aw[j]);
    }
    bf16x8 v;
#pragma unroll
    for (int j = 0; j < 8; ++j) v[j] = (bf16)aw[j];
    *(bf16x8*)((bf16*)(ws + OFF_W3P) + (size_t)e * 8) = v;
  } else if (gid < 10752) {
    const int e = gid - 8704;
    const int lane = e & 63, tt = e >> 6;
    const int nt = tt & 15, kt = tt >> 4;
    const int m = nt * 16 + (lane & 15);
    const int k0 = kt * 32 + ((lane >> 4) << 3);
    bf16x8 v;
#pragma unroll
    for (int j = 0; j < 8; ++j) v[j] = (bf16)W1[(k0 + j) * HID + m];
    *(bf16x8*)((bf16*)(ws + OFF_W1P) + (size_t)e * 8) = v;
  } else if (gid < 11008) {
    const int h = gid - 10752;
    ((float*)(ws + OFF_B1E))[h] = b1[h] + t[0] * W1[SDIM * HID + h];  // fold t-col
  } else if (gid < 11024) {
    const int c = gid - 11008;
    float s = 0.f;
    for (int m = 0; m < SDIM; ++m) s = fmaf(b3[m], Bmat[m * CDIM + c], s);
    ((float*)(ws + OFF_B3B))[c] = s;
  }
}

// ---- main: 512 blocks x 256 threads (4 waves), 76.8 KB LDS -> 2 blocks/CU ----
__global__ __launch_bounds__(256, 2)
void oc_main(const float* __restrict__ x, const float* __restrict__ b2,
             const char* __restrict__ ws, float* __restrict__ out) {
  __shared__ bf16 sH1[BM * LDH];   // H1 [batch][hidden]; reused as H2-lo
  __shared__ bf16 sH2[BM * LDH];   // H2-hi
  __shared__ bf16 sX [BM * LDX];   // staged X [batch][k]
  const int tid  = threadIdx.x;
  const int wave = tid >> 6, lane = tid & 63;
  const int q    = lane >> 4, l = lane & 15;

  const bf16* W2p = (const bf16*)(ws + OFF_W2P);
  const bf16* W3p = (const bf16*)(ws + OFF_W3P);
  const bf16* W1p = (const bf16*)(ws + OFF_W1P);

  // ---- initial X stage: 1024 float4, 4 per thread ----
  {
    const float* xp = x + (size_t)blockIdx.x * BM * SDIM;
#pragma unroll
    for (int i = 0; i < 4; ++i) {
      const int e = i * 256 + tid;           // 1024 float4 = 64 x 64 floats
      const int r = e >> 4, k4 = (e & 15) * 4;
      const float4 v = *(const float4*)(xp + r * SDIM + k4);
      bf16x4 w = {(bf16)v.x, (bf16)v.y, (bf16)v.z, (bf16)v.w};
      *(bf16x4*)(&sX[r * LDX + k4]) = w;
    }
  }

  // ---- biases: wave owns 64 hidden (mt 0..3), h0 = 64*wave + 16*mt + 4*q ----
  f32x4 b1e[4], b2e[4];
#pragma unroll
  for (int mt = 0; mt < 4; ++mt) {
    const int h0 = 64 * wave + 16 * mt + 4 * q;
    const float4 v1 = *(const float4*)((const float*)(ws + OFF_B1E) + h0);
    const float4 v2 = *(const float4*)(b2 + h0);
    b1e[mt] = (f32x4){v1.x, v1.y, v1.z, v1.w};
    b2e[mt] = (f32x4){v2.x, v2.y, v2.z, v2.w};
  }
  f32x4 b3t;
  {
    const float4 v = *(const float4*)((const float*)(ws + OFF_B3B) + 4 * q);
    b3t = (f32x4){v.x, v.y, v.z, v.w};
  }
  __syncthreads();   // sX staged

  f32x4 acc[4][4];   // [mt][nt] -> 64 AGPRs

  for (int it = 0; it < ITERS; ++it) {
    const int tile = blockIdx.x + it * GRID;

    // ---- layer 1: H1 = relu(W1^T X^T + b1); M=64 hidden/wave, N=64 batch ----
#pragma unroll
    for (int mt = 0; mt < 4; ++mt)
#pragma unroll
      for (int nt = 0; nt < 4; ++nt) acc[mt][nt] = b1e[mt];
#pragma unroll
    for (int kt = 0; kt < 2; ++kt) {
      bf16x8 w1f[4];
#pragma unroll
      for (int mt = 0; mt < 4; ++mt)
        w1f[mt] = *(const bf16x8*)(W1p + ((size_t)(kt * 16 + 4 * wave + mt) * 64 + lane) * 8);
#pragma unroll
      for (int nt = 0; nt < 4; ++nt) {
        const bf16x8 b = *(const bf16x8*)(&sX[(16 * nt + l) * LDX + 32 * kt + 8 * q]);
#pragma unroll
        for (int mt = 0; mt < 4; ++mt) acc[mt][nt] = MFMA(w1f[mt], b, acc[mt][nt]);
      }
    }
#pragma unroll
    for (int mt = 0; mt < 4; ++mt) {
      const int h0 = 64 * wave + 16 * mt + 4 * q;
#pragma unroll
      for (int nt = 0; nt < 4; ++nt) {
        bf16x4 v;
#pragma unroll
        for (int r = 0; r < 4; ++r) v[r] = (bf16)fmaxf(acc[mt][nt][r], 0.f);
        *(bf16x4*)(&sH1[sh_idx(16 * nt + l, h0)]) = v;
      }
    }
    __syncthreads();   // A: H1 visible; sX reads done

    // ---- layer 2: H2 = relu(W2^T H1 + b2)  K=256; W2 frags streamed from ws ----
#pragma unroll
    for (int mt = 0; mt < 4; ++mt)
#pragma unroll
      for (int nt = 0; nt < 4; ++nt) acc[mt][nt] = b2e[mt];
#pragma unroll
    for (int kt = 0; kt < 8; ++kt) {
      bf16x8 w2f[4];
#pragma unroll
      for (int mt = 0; mt < 4; ++mt)
        w2f[mt] = *(const bf16x8*)(W2p + ((size_t)(kt * 16 + 4 * wave + mt) * 64 + lane) * 8);
#pragma unroll
      for (int nt = 0; nt < 4; ++nt) {
        const bf16x8 b = *(const bf16x8*)(&sH1[sh_idx(16 * nt + l, 32 * kt + 8 * q)]);
#pragma unroll
        for (int mt = 0; mt < 4; ++mt) acc[mt][nt] = MFMA(w2f[mt], b, acc[mt][nt]);
      }
    }
    __syncthreads();   // B: sH1 reads done -> overwritable as H2-lo

    // ---- H2 writeback: hi (sH2) + lo residual (sH1), b64 each ----
#pragma unroll
    for (int mt = 0; mt < 4; ++mt) {
      const int h0 = 64 * wave + 16 * mt + 4 * q;
#pragma unroll
      for (int nt = 0; nt < 4; ++nt) {
        bf16x4 hi, lo;
#pragma unroll
        for (int r = 0; r < 4; ++r) {
          const float v = fmaxf(acc[mt][nt][r], 0.f);
          const bf16 h = (bf16)v;
          hi[r] = h;
          lo[r] = (bf16)(v - (float)h);
        }
        const int idx = sh_idx(16 * nt + l, h0);
        *(bf16x4*)(&sH2[idx]) = hi;
        *(bf16x4*)(&sH1[idx]) = lo;
      }
    }
    __syncthreads();   // C: H2 hi/lo visible

    if (wave < 2) {
      // ---- layer 3 (waves 0-1): 32 rows/wave, two 16-row groups ----
#pragma unroll
      for (int g = 0; g < 2; ++g) {
        const int row = 32 * wave + 16 * g + l;
        f32x4 a3 = b3t;
#pragma unroll
        for (int kt = 0; kt < 8; ++kt) {
          const bf16x8 w3 = *(const bf16x8*)(W3p + ((size_t)kt * 64 + lane) * 8);
          const int idx = sh_idx(row, 32 * kt + 8 * q);
          const bf16x8 bh = *(const bf16x8*)(&sH2[idx]);
          const bf16x8 bl = *(const bf16x8*)(&sH1[idx]);
          a3 = MFMA(w3, bh, a3);
          a3 = MFMA(w3, bl, a3);
        }
        f32x4 o;
#pragma unroll
        for (int r = 0; r < 4; ++r)
          o[r] = fminf(fmaxf(-a3[r], -1.f), 1.f);
        *(float4*)(&out[((size_t)tile * BM + row) * CDIM + 4 * q]) = *(float4*)&o;
      }
    } else if (it + 1 < ITERS) {
      // ---- waves 2-3: stage next X tile concurrently with layer 3 ----
      const float* xp = x + (size_t)(tile + GRID) * BM * SDIM;
      const int tid2 = tid - 128;            // 0..127
#pragma unroll
      for (int i = 0; i < 8; ++i) {
        const int e = i * 128 + tid2;        // 1024 float4 = 64 x 64 floats
        const int r = e >> 4, k4 = (e & 15) * 4;
        const float4 v = *(const float4*)(xp + r * SDIM + k4);
        bf16x4 w = {(bf16)v.x, (bf16)v.y, (bf16)v.z, (bf16)v.w};
        *(bf16x4*)(&sX[r * LDX + k4]) = w;
      }
    }
    __syncthreads();   // D: L3 reads + stage done before next L1 overwrites sH1/reads sX
  }
}

extern "C" void kernel_launch(void* const* d_in, const int* in_sizes, int n_in,
                              void* d_out, int out_size, void* d_ws, size_t ws_size,
                              hipStream_t stream) {
  const float* x    = (const float*)d_in[0];
  const float* t    = (const float*)d_in[1];
  const float* W1   = (const float*)d_in[2];
  const float* b1   = (const float*)d_in[3];
  const float* W2   = (const float*)d_in[4];
  const float* b2   = (const float*)d_in[5];
  const float* W3   = (const float*)d_in[6];
  const float* b3   = (const float*)d_in[7];
  const float* Bmat = (const float*)d_in[8];
  float* out = (float*)d_out;
  char*  ws  = (char*)d_ws;

  hipLaunchKernelGGL(oc_pack, dim3(22), dim3(512), 0, stream,
                     t, W1, b1, W2, W3, b3, Bmat, ws);
  hipLaunchKernelGGL(oc_main, dim3(GRID), dim3(256), 0, stream,
                     x, b2, ws, out);
}

// Round 12
// 125.933 us; speedup vs baseline: 1.7749x; 1.2865x over previous
//
#include <hip/hip_runtime.h>

// ImplicitNetOC: u = clip(-pB) ; pB = relu(relu([x,t]W1+b1)W2+b2) @ (W3@Bmat) + b3@Bmat
// R12 = R8 structure in the ONLY spill-free envelope found (512 thr, launch_bounds
// (512,2); R6/R7/R9/R10/R11 all spilled at tighter budgets), with:
//  (a) BM=128 (ITERS=2): halves barrier events/CU, doubles independent MFMA per
//      phase for latency hiding at the fixed 8-wave occupancy;
//  (b) power-of-2 LDS strides + XOR granule swizzle (row stride 128 dw == 0 mod 32
//      banks, so the XOR bijection alone spreads banks; all access classes
//      hand-checked to <=2-way). LDS 144 KB.

typedef __bf16 bf16;
typedef __bf16 bf16x8 __attribute__((ext_vector_type(8)));
typedef __bf16 bf16x4 __attribute__((ext_vector_type(4)));
typedef float  f32x4  __attribute__((ext_vector_type(4)));

#define HID    256
#define SDIM   64
#define CDIM   16
#define BM     128
#define GRID   512      // 1024 tiles / ITERS
#define ITERS  2
// sH row: 256 bf16 (512 B); sX row: 64 bf16 (128 B); 16B granules XOR-swizzled.

// ws byte offsets (pack format unchanged from R8)
#define OFF_W2P 0        // 8192 entries x 16 B (8kt x 16nt x 64lane)
#define OFF_W3P 131072   // 512 entries x 16 B (8kt x 64lane)
#define OFF_W1P 139264   // 2048 entries x 16 B (2kt x 16nt x 64lane)
#define OFF_B1E 172032   // 256 f32
#define OFF_B3B 173056   // 16 f32

#define MFMA(a, b, c) __builtin_amdgcn_mfma_f32_16x16x32_bf16(a, b, c, 0, 0, 0)

// swizzled sH index: element (row=batch, h=hidden). granule = 8 bf16 = 16 B.
__device__ __forceinline__ int sh_idx(int row, int h) {
  return (row << 8) + ((((h >> 3) ^ row) & 7) << 3) + (h & 7) + ((h >> 6) << 6);
}
// NOTE: h < 256, granules per row = 32; swizzle only the low 3 granule bits:
// idx = row*256 + (g & ~7)*8 + ((g&7)^(row&7))*8 + (h&7), g = h>>3.
// The expression above computes exactly that: ((h>>3)^row)&7 gives swizzled low
// bits; (h>>6)<<6 restores the high granule bits (g>>3 worth 64 bf16 each).

__device__ __forceinline__ int sx_idx(int row, int k) {
  return (row << 6) + ((((k >> 3) ^ row) & 7) << 3) + (k & 7);
}

// ---- pack kernel: W2/W1/W3B A-frags + folded biases -> ws. 22 x 512 ----
__global__ __launch_bounds__(512)
void oc_pack(const float* __restrict__ t,  const float* __restrict__ W1,
             const float* __restrict__ b1, const float* __restrict__ W2,
             const float* __restrict__ W3, const float* __restrict__ b3,
             const float* __restrict__ Bmat, char* __restrict__ ws) {
  const int gid = blockIdx.x * 512 + threadIdx.x;
  if (gid < 8192) {
    const int lane = gid & 63, tt = gid >> 6;
    const int nt = tt & 15, kt = tt >> 4;
    const int m = nt * 16 + (lane & 15);
    const int k0 = kt * 32 + ((lane >> 4) << 3);
    bf16x8 v;
#pragma unroll
    for (int j = 0; j < 8; ++j) v[j] = (bf16)W2[(k0 + j) * HID + m];
    *(bf16x8*)((bf16*)(ws + OFF_W2P) + (size_t)gid * 8) = v;
  } else if (gid < 8704) {
    const int e = gid - 8192, kt = e >> 6, fl = e & 63;
    const int r0 = kt * 32 + ((fl >> 4) << 3);
    const int c  = fl & 15;
    float aw[8];
#pragma unroll
    for (int j = 0; j < 8; ++j) aw[j] = 0.f;
    for (int m = 0; m < SDIM; ++m) {
      const float bm = Bmat[m * CDIM + c];
#pragma unroll
      for (int j = 0; j < 8; ++j) aw[j] = fmaf(W3[(r0 + j) * SDIM + m], bm, aw[j]);
    }
    bf16x8 v;
#pragma unroll
    for (int j = 0; j < 8; ++j) v[j] = (bf16)aw[j];
    *(bf16x8*)((bf16*)(ws + OFF_W3P) + (size_t)e * 8) = v;
  } else if (gid < 10752) {
    const int e = gid - 8704;
    const int lane = e & 63, tt = e >> 6;
    const int nt = tt & 15, kt = tt >> 4;
    const int m = nt * 16 + (lane & 15);
    const int k0 = kt * 32 + ((lane >> 4) << 3);
    bf16x8 v;
#pragma unroll
    for (int j = 0; j < 8; ++j) v[j] = (bf16)W1[(k0 + j) * HID + m];
    *(bf16x8*)((bf16*)(ws + OFF_W1P) + (size_t)e * 8) = v;
  } else if (gid < 11008) {
    const int h = gid - 10752;
    ((float*)(ws + OFF_B1E))[h] = b1[h] + t[0] * W1[SDIM * HID + h];  // fold t-col
  } else if (gid < 11024) {
    const int c = gid - 11008;
    float s = 0.f;
    for (int m = 0; m < SDIM; ++m) s = fmaf(b3[m], Bmat[m * CDIM + c], s);
    ((float*)(ws + OFF_B3B))[c] = s;
  }
}

// ---- main: 512 blocks x 512 threads (8 waves), 144 KB LDS, 1 block/CU ----
__global__ __launch_bounds__(512, 2)
void oc_main(const float* __restrict__ x, const float* __restrict__ b2,
             const char* __restrict__ ws, float* __restrict__ out) {
  __shared__ bf16 sH1[BM * 256];   // H1 [batch][hidden] swizzled; reused as H2-lo
  __shared__ bf16 sH2[BM * 256];   // H2-hi
  __shared__ bf16 sX [BM * 64];    // staged X [batch][k] swizzled
  const int tid  = threadIdx.x;
  const int wave = tid >> 6, lane = tid & 63;
  const int q    = lane >> 4, l = lane & 15;

  const bf16* W2p = (const bf16*)(ws + OFF_W2P);
  const bf16* W3p = (const bf16*)(ws + OFF_W3P);
  const bf16* W1p = (const bf16*)(ws + OFF_W1P);

  // ---- initial X stage: 2048 float4, 4 per thread ----
  {
    const float* xp = x + (size_t)blockIdx.x * BM * SDIM;
#pragma unroll
    for (int i = 0; i < 4; ++i) {
      const int e = i * 512 + tid;           // 2048 float4 = 128 x 64 floats
      const int r = e >> 4, k4 = (e & 15) * 4;
      const float4 v = *(const float4*)(xp + r * SDIM + k4);
      bf16x4 w = {(bf16)v.x, (bf16)v.y, (bf16)v.z, (bf16)v.w};
      *(bf16x4*)(&sX[sx_idx(r, k4)]) = w;
    }
  }

  // ---- biases: wave owns 32 hidden (mt 0..1), h0 = 32*wave + 16*mt + 4*q ----
  f32x4 b1e[2], b2e[2];
#pragma unroll
  for (int mt = 0; mt < 2; ++mt) {
    const int h0 = 32 * wave + 16 * mt + 4 * q;
    const float4 v1 = *(const float4*)((const float*)(ws + OFF_B1E) + h0);
    const float4 v2 = *(const float4*)(b2 + h0);
    b1e[mt] = (f32x4){v1.x, v1.y, v1.z, v1.w};
    b2e[mt] = (f32x4){v2.x, v2.y, v2.z, v2.w};
  }
  f32x4 b3t;
  {
    const float4 v = *(const float4*)((const float*)(ws + OFF_B3B) + 4 * q);
    b3t = (f32x4){v.x, v.y, v.z, v.w};
  }
  __syncthreads();   // sX staged

  f32x4 acc[2][8];   // [mt][nt]

  for (int it = 0; it < ITERS; ++it) {
    const int tile = blockIdx.x + it * GRID;

    // ---- layer 1: H1 = relu(W1^T X^T + b1); M=32 hidden/wave, N=128 batch ----
#pragma unroll
    for (int mt = 0; mt < 2; ++mt)
#pragma unroll
      for (int nt = 0; nt < 8; ++nt) acc[mt][nt] = b1e[mt];
#pragma unroll
    for (int kt = 0; kt < 2; ++kt) {
      const bf16x8 w1a = *(const bf16x8*)(W1p + ((size_t)(kt * 16 + 2 * wave    ) * 64 + lane) * 8);
      const bf16x8 w1b = *(const bf16x8*)(W1p + ((size_t)(kt * 16 + 2 * wave + 1) * 64 + lane) * 8);
#pragma unroll
      for (int nt = 0; nt < 8; ++nt) {
        const bf16x8 b = *(const bf16x8*)(&sX[sx_idx(16 * nt + l, 32 * kt + 8 * q)]);
        acc[0][nt] = MFMA(w1a, b, acc[0][nt]);
        acc[1][nt] = MFMA(w1b, b, acc[1][nt]);
      }
    }
#pragma unroll
    for (int mt = 0; mt < 2; ++mt) {
      const int h0 = 32 * wave + 16 * mt + 4 * q;
#pragma unroll
      for (int nt = 0; nt < 8; ++nt) {
        bf16x4 v;
#pragma unroll
        for (int r = 0; r < 4; ++r) v[r] = (bf16)fmaxf(acc[mt][nt][r], 0.f);
        *(bf16x4*)(&sH1[sh_idx(16 * nt + l, h0)]) = v;
      }
    }
    __syncthreads();   // A: H1 visible; sX reads done

    // ---- layer 2: H2 = relu(W2^T H1 + b2)  K=256; W2 frags streamed from ws ----
#pragma unroll
    for (int mt = 0; mt < 2; ++mt)
#pragma unroll
      for (int nt = 0; nt < 8; ++nt) acc[mt][nt] = b2e[mt];
#pragma unroll
    for (int kt = 0; kt < 8; ++kt) {
      const bf16x8 w2a = *(const bf16x8*)(W2p + ((size_t)(kt * 16 + 2 * wave    ) * 64 + lane) * 8);
      const bf16x8 w2b = *(const bf16x8*)(W2p + ((size_t)(kt * 16 + 2 * wave + 1) * 64 + lane) * 8);
#pragma unroll
      for (int nt = 0; nt < 8; ++nt) {
        const bf16x8 b = *(const bf16x8*)(&sH1[sh_idx(16 * nt + l, 32 * kt + 8 * q)]);
        acc[0][nt] = MFMA(w2a, b, acc[0][nt]);
        acc[1][nt] = MFMA(w2b, b, acc[1][nt]);
      }
    }
    __syncthreads();   // B: sH1 reads done -> overwritable as H2-lo

    // ---- H2 writeback: hi (sH2) + lo residual (sH1), b64 each ----
#pragma unroll
    for (int mt = 0; mt < 2; ++mt) {
      const int h0 = 32 * wave + 16 * mt + 4 * q;
#pragma unroll
      for (int nt = 0; nt < 8; ++nt) {
        bf16x4 hi, lo;
#pragma unroll
        for (int r = 0; r < 4; ++r) {
          const float v = fmaxf(acc[mt][nt][r], 0.f);
          const bf16 h = (bf16)v;
          hi[r] = h;
          lo[r] = (bf16)(v - (float)h);
        }
        const int idx = sh_idx(16 * nt + l, h0);
        *(bf16x4*)(&sH2[idx]) = hi;
        *(bf16x4*)(&sH1[idx]) = lo;
      }
    }
    __syncthreads();   // C: H2 hi/lo visible

    if (wave < 4) {
      // ---- layer 3 (waves 0-3): 32 rows/wave, two 16-row groups ----
#pragma unroll
      for (int g = 0; g < 2; ++g) {
        const int row = 32 * wave + 16 * g + l;
        f32x4 a3 = b3t;
#pragma unroll
        for (int kt = 0; kt < 8; ++kt) {
          const bf16x8 w3 = *(const bf16x8*)(W3p + ((size_t)kt * 64 + lane) * 8);
          const int idx = sh_idx(row, 32 * kt + 8 * q);
          const bf16x8 bh = *(const bf16x8*)(&sH2[idx]);
          const bf16x8 bl = *(const bf16x8*)(&sH1[idx]);
          a3 = MFMA(w3, bh, a3);
          a3 = MFMA(w3, bl, a3);
        }
        f32x4 o;
#pragma unroll
        for (int r = 0; r < 4; ++r)
          o[r] = fminf(fmaxf(-a3[r], -1.f), 1.f);
        *(float4*)(&out[((size_t)tile * BM + row) * CDIM + 4 * q]) = *(float4*)&o;
      }
    } else if (it + 1 < ITERS) {
      // ---- waves 4-7: stage next X tile concurrently with layer 3 ----
      const float* xp = x + (size_t)(tile + GRID) * BM * SDIM;
      const int tid2 = tid - 256;            // 0..255
#pragma unroll
      for (int i = 0; i < 8; ++i) {
        const int e = i * 256 + tid2;        // 2048 float4 = 128 x 64 floats
        const int r = e >> 4, k4 = (e & 15) * 4;
        const float4 v = *(const float4*)(xp + r * SDIM + k4);
        bf16x4 w = {(bf16)v.x, (bf16)v.y, (bf16)v.z, (bf16)v.w};
        *(bf16x4*)(&sX[sx_idx(r, k4)]) = w;
      }
    }
    __syncthreads();   // D: L3 reads + stage done before next L1 overwrites sH1/reads sX
  }
}

extern "C" void kernel_launch(void* const* d_in, const int* in_sizes, int n_in,
                              void* d_out, int out_size, void* d_ws, size_t ws_size,
                              hipStream_t stream) {
  const float* x    = (const float*)d_in[0];
  const float* t    = (const float*)d_in[1];
  const float* W1   = (const float*)d_in[2];
  const float* b1   = (const float*)d_in[3];
  const float* W2   = (const float*)d_in[4];
  const float* b2   = (const float*)d_in[5];
  const float* W3   = (const float*)d_in[6];
  const float* b3   = (const float*)d_in[7];
  const float* Bmat = (const float*)d_in[8];
  float* out = (float*)d_out;
  char*  ws  = (char*)d_ws;

  hipLaunchKernelGGL(oc_pack, dim3(22), dim3(512), 0, stream,
                     t, W1, b1, W2, W3, b3, Bmat, ws);
  hipLaunchKernelGGL(oc_main, dim3(GRID), dim3(512), 0, stream,
                     x, b2, ws, out);
}